// Round 10
// baseline (145.551 us; speedup 1.0000x reference)
//
#include <hip/hip_runtime.h>
#include <math.h>

#define CC 256
#define NPIX 4096
#define BATCH 4
#define LOG2E 1.4426950408889634f

typedef __attribute__((ext_vector_type(8)))  short short8;
typedef __attribute__((ext_vector_type(8)))  int   int32x8;
typedef __attribute__((ext_vector_type(16))) float f32x16;

union FragU { short8 v; short s[8]; unsigned u[4]; uint2 d[2]; };
union V8  { uint4 q[2]; int32x8 iv; };
union B8  { unsigned u[8]; int32x8 iv; };

__device__ inline unsigned pkbf(float a, float b) {   // pack 2 floats -> 2 bf16 (RNE)
    unsigned x = __float_as_uint(a), y = __float_as_uint(b);
    x = (x + 0x7FFFu + ((x >> 16) & 1u)) >> 16;
    y = (y + 0x7FFFu + ((y >> 16) & 1u)) & 0xFFFF0000u;
    return x | y;
}
__device__ inline unsigned short bf1(float a) {
    unsigned x = __float_as_uint(a);
    return (unsigned short)((x + 0x7FFFu + ((x >> 16) & 1u)) >> 16);
}
__device__ inline float ex2(float x) { return __builtin_amdgcn_exp2f(x); }
__device__ inline unsigned pk4fp8(float a, float b, float c, float d) {
    int r = __builtin_amdgcn_cvt_pk_fp8_f32(a, b, 0, false);
    r = __builtin_amdgcn_cvt_pk_fp8_f32(c, d, r, true);
    return (unsigned)r;
}
__device__ inline f32x16 zero16() {
    f32x16 v;
    #pragma unroll
    for (int i = 0; i < 16; ++i) v[i] = 0.0f;
    return v;
}
__device__ inline f32x16 mfma32(short8 a, short8 b, f32x16 c) {
    return __builtin_amdgcn_mfma_f32_32x32x16_bf16(a, b, c, 0, 0, 0);
}
// MX-scaled fp8 K=64, identity scales (e8m0 0x7F = 2^0)
__device__ inline f32x16 mfma64s(int32x8 a, int32x8 b, f32x16 c) {
    return __builtin_amdgcn_mfma_scale_f32_32x32x64_f8f6f4(
        a, b, c, 0 /*cbsz: fp8*/, 0 /*blgp: fp8*/, 0, 0x7F, 0, 0x7F);
}

// ---------------------------------------------------------------------------
// prep: blocks 0..255: transpose+bf16 x -> xT[b][p][c] (via LDS).
//       blocks 256..295: pack W -> Wfrag[gs][lane][8] in MFMA B-frag order.
// ---------------------------------------------------------------------------
__global__ __launch_bounds__(256, 2) void prep_kernel(
    const float* __restrict__ x,
    const float* __restrict__ Wq, const float* __restrict__ Wk,
    const float* __restrict__ Wv,
    unsigned short* __restrict__ xT, unsigned short* __restrict__ Wfrag)
{
    const int t = threadIdx.x;
    const int bid = blockIdx.x;
    if (bid < 256) {
        __shared__ unsigned short xs[256 * 68];
        const int b = bid >> 6, u = bid & 63;
        const int p0 = u * 64;
        const float* xb = x + (size_t)b * CC * NPIX + p0;
        #pragma unroll
        for (int k = 0; k < 16; ++k) {
            int c = (t >> 4) + 16 * k;
            int p4 = (t & 15) * 4;
            float4 v = *(const float4*)(xb + (size_t)c * NPIX + p4);
            *(uint2*)&xs[c * 68 + p4] = make_uint2(pkbf(v.x, v.y), pkbf(v.z, v.w));
        }
        __syncthreads();
        const int w = t >> 6, l = t & 63;
        const int c8 = l & 31;
        #pragma unroll
        for (int i = 0; i < 8; ++i) {
            int p = i * 8 + w * 2 + (l >> 5);
            unsigned short tmp[8];
            #pragma unroll
            for (int j = 0; j < 8; ++j) tmp[j] = xs[(c8 * 8 + j) * 68 + p];
            uint4 o;
            o.x = tmp[0] | ((unsigned)tmp[1] << 16);
            o.y = tmp[2] | ((unsigned)tmp[3] << 16);
            o.z = tmp[4] | ((unsigned)tmp[5] << 16);
            o.w = tmp[6] | ((unsigned)tmp[7] << 16);
            *(uint4*)(xT + (size_t)(b * NPIX + p0 + p) * 256 + c8 * 8) = o;
        }
    } else {
        const int wb = bid - 256;            // 0..39
        const int l = t & 63, rr = t >> 6;   // rr 0..3
        #pragma unroll
        for (int e = 0; e < 4; ++e) {
            int gs = wb * 4 + e;             // 0..159
            int g = gs >> 4, s = gs & 15;
            const float* src; float scale = 1.0f; int oc0 = 0;
            if (g == 0)      { src = Wq; scale = LOG2E; }
            else if (g == 1) { src = Wk; }
            else             { src = Wv; oc0 = (g - 2) * 32; }
            int row = oc0 + (l & 31);
            int kb2 = 16 * s + 8 * (l >> 5) + rr * 2;
            float v0 = src[(size_t)row * CC + kb2] * scale;
            float v1 = src[(size_t)row * CC + kb2 + 1] * scale;
            *(unsigned*)(Wfrag + (size_t)(gs * 64 + l) * 8 + rr * 2) = pkbf(v0, v1);
        }
    }
}

// ---------------------------------------------------------------------------
// proj: block = 5 waves (320 thr) sharing one LDS x-tile; wave = one ocg x
// 64 px. qT/kT bf16 (q pre-scaled log2e); V written fp8-e4m3 into
// vI[b][j64][cg][lane: jhalf*32+c][32B] (byte = j&31 — K=64 A-frag order).
// ---------------------------------------------------------------------------
__global__ __launch_bounds__(320, 3) void proj_mfma(
    const unsigned short* __restrict__ xT, const unsigned short* __restrict__ Wfrag,
    const float* __restrict__ mask,
    const float* __restrict__ bq, const float* __restrict__ bk,
    const float* __restrict__ bv,
    unsigned short* __restrict__ qT, unsigned short* __restrict__ kT,
    unsigned char* __restrict__ vI)
{
    __shared__ unsigned short xls[64 * 260];
    const int t = threadIdx.x;
    const int w = t >> 6, l = t & 63, L = l & 31, h = l >> 5;
    const int bid = blockIdx.x;
    const int b    = (bid >> 1) & 3;                 // XCD-pinned by batch
    const int u    = ((bid >> 3) << 1) | (bid & 1);  // 0..127
    const int p0   = (u >> 1) * 64;
    const int half = u & 1;
    const int ocg  = half * 5 + w;                   // 0=q 1=k 2..4 / 5..9 v

    const unsigned short* xg = xT + (size_t)(b * NPIX + p0) * 256;
    #pragma unroll
    for (int r = 0; r < 7; ++r) {
        int idx = r * 2560 + t * 8;
        if (idx < 16384) {
            uint4 d = *(const uint4*)(xg + idx);
            int p = idx >> 8, c = idx & 255;
            *(uint2*)&xls[p * 260 + c]     = make_uint2(d.x, d.y);
            *(uint2*)&xls[p * 260 + c + 4] = make_uint2(d.z, d.w);
        }
    }

    FragU wf[16];
    const unsigned short* wp = Wfrag + (size_t)(ocg * 16 * 64 + l) * 8;
    #pragma unroll
    for (int s = 0; s < 16; ++s) wf[s].v = *(const short8*)(wp + s * 512);

    float bcol;
    if (ocg == 0)      bcol = bq[L] * LOG2E;
    else if (ocg == 1) bcol = bk[L];
    else               bcol = bv[(ocg - 2) * 32 + L];
    const float* mb = mask + (size_t)b * NPIX;
    __syncthreads();

    #pragma unroll
    for (int mt = 0; mt < 2; ++mt) {
        const int pp = 32 * mt;
        f32x16 acc = zero16();
        #pragma unroll
        for (int s = 0; s < 16; ++s) {
            FragU af;
            const unsigned short* ap = &xls[(pp + L) * 260 + 16 * s + 8 * h];
            af.d[0] = *(const uint2*)(ap);
            af.d[1] = *(const uint2*)(ap + 4);
            acc = mfma32(af.v, wf[s].v, acc);
        }
        if (ocg < 2) {
            unsigned short* dst = (ocg ? kT : qT) + (size_t)b * NPIX * 32;
            #pragma unroll
            for (int r = 0; r < 16; ++r) {
                int prow = (r & 3) + 8 * (r >> 2) + 4 * h;
                float mv = mb[p0 + pp + prow];
                dst[(size_t)(p0 + pp + prow) * 32 + L] = bf1((acc[r] + bcol) * mv);
            }
        } else {
            const int cg = ocg - 2;
            const int jb32 = p0 + pp;                // 32-j block base
            unsigned char* dst = vI + (size_t)b * (1 << 20)
                + (size_t)(jb32 >> 6) * 16384 + cg * 2048
                + (((jb32 >> 5) & 1) * 32 + L) * 32 + 4 * h;
            #pragma unroll
            for (int m = 0; m < 4; ++m) {
                unsigned pk = pk4fp8(acc[4*m]   + bcol, acc[4*m+1] + bcol,
                                     acc[4*m+2] + bcol, acc[4*m+3] + bcol);
                *(unsigned*)(dst + 8 * m) = pk;
            }
        }
    }
}

// ---------------------------------------------------------------------------
// attn: channel-split occupancy build. Block = (batch, 32-q tile, 128-channel
// half); wave = 1024-j quarter. acc[4] (64 VGPR) -> 3 waves/SIMD. S/softmax
// duplicated across the 2 channel-halves (cheap); PV via MX-scaled fp8 K=64.
// ---------------------------------------------------------------------------
__global__ __launch_bounds__(256, 3) void attn_mfma(
    const unsigned short* __restrict__ qT, const unsigned short* __restrict__ kT,
    const unsigned char* __restrict__ vI, const float* __restrict__ x,
    const float* __restrict__ gamma, float* __restrict__ out)
{
    __shared__ float mls[2][4][32];
    __shared__ float obuf[4][2048];

    const int t = threadIdx.x;
    const int w = t >> 6, l = t & 63, L = l & 31, h = l >> 5;
    const int bid = blockIdx.x;
    const int b  = (bid >> 1) & 3;                 // XCD-pinned by batch
    const int ch = (bid >> 3) & 1;                 // channel half
    const int it = (bid >> 4) * 2 + (bid & 1);     // 0..127
    const int i0 = it * 32;

    const unsigned short* qrow = qT + ((size_t)b * NPIX + i0 + L) * 32 + 8 * h;
    short8 qf0 = *(const short8*)(qrow);
    short8 qf1 = *(const short8*)(qrow + 16);

    const int jbase = w * 1024;
    // K stream: one byte pointer, advanced 4096 B/iter; imm offsets 0/32/2048/2080
    const unsigned char* kp = (const unsigned char*)kT
        + (size_t)b * NPIX * 64 + (size_t)jbase * 64 + (size_t)L * 64 + 16 * h;
    short8 ka0 = *(const short8*)(kp);
    short8 ka1 = *(const short8*)(kp + 32);
    short8 kb0 = *(const short8*)(kp + 2048);
    short8 kb1 = *(const short8*)(kp + 2080);
    kp += 4096;
    // V stream: this block's 4 c-groups at imm offsets cg*2048
    const unsigned char* vp = vI + (size_t)b * (1 << 20)
        + (size_t)(jbase >> 6) * 16384 + ch * 4 * 2048 + (size_t)l * 32;

    f32x16 acc[4];
    #pragma unroll
    for (int cg = 0; cg < 4; ++cg) acc[cg] = zero16();
    float m_run = -INFINITY, l_run = 0.0f;

    for (int itr = 0; itr < 16; ++itr) {
        // ---- S(n) ----
        f32x16 s0 = zero16(), s1 = zero16();
        s0 = mfma32(ka0, qf0, s0);
        s0 = mfma32(ka1, qf1, s0);
        s1 = mfma32(kb0, qf0, s1);
        s1 = mfma32(kb1, qf1, s1);

        // ---- K prefetch (n+1) ----  (last iter reads past kT: valid ws mem)
        ka0 = *(const short8*)(kp);
        ka1 = *(const short8*)(kp + 32);
        kb0 = *(const short8*)(kp + 2048);
        kb1 = *(const short8*)(kp + 2080);
        kp += 4096;

        // ---- V loads (4 cg) — covered by softmax below ----
        V8 vv[4];
        #pragma unroll
        for (int cg = 0; cg < 4; ++cg) {
            vv[cg].q[0] = *(const uint4*)(vp + cg * 2048);
            vv[cg].q[1] = *(const uint4*)(vp + cg * 2048 + 16);
        }
        vp += 16384;

        // ---- wave-local online softmax (exp2 domain, hysteresis, trees) ----
        float t0 = s0[0], t1 = s0[1], t2 = s0[2], t3 = s0[3];
        #pragma unroll
        for (int r = 4; r < 16; r += 4) {
            t0 = fmaxf(t0, s0[r]);     t1 = fmaxf(t1, s0[r + 1]);
            t2 = fmaxf(t2, s0[r + 2]); t3 = fmaxf(t3, s0[r + 3]);
        }
        #pragma unroll
        for (int r = 0; r < 16; r += 4) {
            t0 = fmaxf(t0, s1[r]);     t1 = fmaxf(t1, s1[r + 1]);
            t2 = fmaxf(t2, s1[r + 2]); t3 = fmaxf(t3, s1[r + 3]);
        }
        float tmax = fmaxf(fmaxf(t0, t1), fmaxf(t2, t3));
        tmax = fmaxf(tmax, __shfl_xor(tmax, 32));
        if (__ballot(tmax > m_run + 3.0f)) {
            float m_new = fmaxf(m_run, tmax);
            float alpha = ex2(m_run - m_new);   // first iter: ex2(-inf)=0
            l_run *= alpha;
            #pragma unroll
            for (int cg = 0; cg < 4; ++cg)
                #pragma unroll
                for (int r = 0; r < 16; ++r) acc[cg][r] *= alpha;
            m_run = m_new;
        }

        float z0 = 0, z1 = 0, z2 = 0, z3 = 0;
        #pragma unroll
        for (int r = 0; r < 16; r += 4) {
            s0[r]   = ex2(s0[r]   - m_run); z0 += s0[r];
            s0[r+1] = ex2(s0[r+1] - m_run); z1 += s0[r+1];
            s0[r+2] = ex2(s0[r+2] - m_run); z2 += s0[r+2];
            s0[r+3] = ex2(s0[r+3] - m_run); z3 += s0[r+3];
        }
        #pragma unroll
        for (int r = 0; r < 16; r += 4) {
            s1[r]   = ex2(s1[r]   - m_run); z0 += s1[r];
            s1[r+1] = ex2(s1[r+1] - m_run); z1 += s1[r+1];
            s1[r+2] = ex2(s1[r+2] - m_run); z2 += s1[r+2];
            s1[r+3] = ex2(s1[r+3] - m_run); z3 += s1[r+3];
        }
        float ssum = (z0 + z1) + (z2 + z3);
        ssum += __shfl_xor(ssum, 32);
        l_run += ssum;

        // ---- pack P, exchange, build K=64 B-frag ----
        unsigned u0[4], u1[4], p0[4], p1[4];
        #pragma unroll
        for (int m = 0; m < 4; ++m) {
            u0[m] = pk4fp8(s0[4*m], s0[4*m+1], s0[4*m+2], s0[4*m+3]);
            u1[m] = pk4fp8(s1[4*m], s1[4*m+1], s1[4*m+2], s1[4*m+3]);
        }
        #pragma unroll
        for (int q = 0; q < 4; ++q) {
            p0[q] = (unsigned)__shfl_xor((int)u0[q], 32);
            p1[q] = (unsigned)__shfl_xor((int)u1[q], 32);
        }
        B8 bf;
        #pragma unroll
        for (int m = 0; m < 4; ++m) {
            unsigned oh = h ? u1[m] : u0[m];
            unsigned ph = h ? p1[m] : p0[m];
            bf.u[2*m]     = h ? ph : oh;   // dword r=2m:   j 8m+0..3
            bf.u[2*m + 1] = h ? oh : ph;   // dword r=2m+1: j 8m+4..7
        }

        // ---- PV: 4 MX-scaled K=64 MFMAs ----
        #pragma unroll
        for (int cg = 0; cg < 4; ++cg) acc[cg] = mfma64s(vv[cg].iv, bf.iv, acc[cg]);
    }

    // ---- merge 4 j-quarter waves ----
    if (h == 0) { mls[0][w][L] = m_run; mls[1][w][L] = l_run; }
    __syncthreads();
    float m0 = mls[0][0][L], m1 = mls[0][1][L], m2 = mls[0][2][L], m3 = mls[0][3][L];
    float ms = fmaxf(fmaxf(m0, m1), fmaxf(m2, m3));
    float f0 = ex2(m0 - ms), f1 = ex2(m1 - ms);
    float f2 = ex2(m2 - ms), f3 = ex2(m3 - ms);
    float lstar = f0 * mls[1][0][L] + f1 * mls[1][1][L]
                + f2 * mls[1][2][L] + f3 * mls[1][3][L];
    float fw = (w == 0) ? f0 : (w == 1) ? f1 : (w == 2) ? f2 : f3;
    const float scale = gamma[0] / lstar;

    #pragma unroll
    for (int cg = 0; cg < 4; ++cg)
        #pragma unroll
        for (int r = 0; r < 16; ++r) acc[cg][r] *= fw;

    const int ti = t & 31, trow = t >> 5;
    #pragma unroll
    for (int ck = 0; ck < 2; ++ck) {
        #pragma unroll
        for (int half = 0; half < 2; ++half) {
            #pragma unroll
            for (int r = 0; r < 16; ++r) {
                int prow = (r & 3) + 8 * (r >> 2) + 4 * h;
                obuf[w][half * 1024 + prow * 32 + L] = acc[2 * ck + half][r];
            }
        }
        __syncthreads();
        #pragma unroll
        for (int rr = 0; rr < 8; ++rr) {
            int cr = trow + 8 * rr;
            int idx = cr * 32 + ti;
            float sum = obuf[0][idx] + obuf[1][idx] + obuf[2][idx] + obuf[3][idx];
            size_t gi = ((size_t)b * CC + ch * 128 + ck * 64 + cr) * NPIX + i0 + ti;
            out[gi] = scale * sum + x[gi];
        }
        __syncthreads();
    }
}

// ---------------------------------------------------------------------------
extern "C" void kernel_launch(void* const* d_in, const int* in_sizes, int n_in,
                              void* d_out, int out_size, void* d_ws, size_t ws_size,
                              hipStream_t stream) {
    const float* x     = (const float*)d_in[0];
    const float* mask  = (const float*)d_in[1];
    const float* Wq    = (const float*)d_in[2];
    const float* bq    = (const float*)d_in[3];
    const float* Wk    = (const float*)d_in[4];
    const float* bk    = (const float*)d_in[5];
    const float* Wv    = (const float*)d_in[6];
    const float* bv    = (const float*)d_in[7];
    const float* gamma = (const float*)d_in[8];
    float* out = (float*)d_out;

    unsigned short* ws = (unsigned short*)d_ws;
    unsigned short* qT = ws;                                   // [B][N][32] bf16
    unsigned short* kT = qT + (size_t)BATCH * NPIX * 32;       // [B][N][32] bf16
    unsigned char*  vI = (unsigned char*)(kT + (size_t)BATCH * NPIX * 32);  // [B][64][8][64][32] fp8
    unsigned short* xT = (unsigned short*)(vI + (size_t)BATCH * CC * NPIX); // [B][N][256] bf16
    unsigned short* Wfrag = xT + (size_t)BATCH * NPIX * 256;   // [160][64][8] bf16

    prep_kernel<<<296, 256, 0, stream>>>(x, Wq, Wk, Wv, xT, Wfrag);
    proj_mfma<<<512, 320, 0, stream>>>(xT, Wfrag, mask, bq, bk, bv, qT, kT, vI);
    attn_mfma<<<1024, 256, 0, stream>>>(qT, kT, vI, x, gamma, out);
}

// Round 11
// 137.442 us; speedup vs baseline: 1.0590x; 1.0590x over previous
//
#include <hip/hip_runtime.h>
#include <math.h>

#define CC 256
#define NPIX 4096
#define BATCH 4
#define LOG2E 1.4426950408889634f

typedef __attribute__((ext_vector_type(8)))  short short8;
typedef __attribute__((ext_vector_type(8)))  int   int32x8;
typedef __attribute__((ext_vector_type(16))) float f32x16;

union FragU { short8 v; short s[8]; unsigned u[4]; uint2 d[2]; };
union V8  { uint4 q[2]; int32x8 iv; };
union B8  { unsigned u[8]; int32x8 iv; };

__device__ inline unsigned pkbf(float a, float b) {   // pack 2 floats -> 2 bf16 (RNE)
    unsigned x = __float_as_uint(a), y = __float_as_uint(b);
    x = (x + 0x7FFFu + ((x >> 16) & 1u)) >> 16;
    y = (y + 0x7FFFu + ((y >> 16) & 1u)) & 0xFFFF0000u;
    return x | y;
}
__device__ inline unsigned short bf1(float a) {
    unsigned x = __float_as_uint(a);
    return (unsigned short)((x + 0x7FFFu + ((x >> 16) & 1u)) >> 16);
}
__device__ inline float ex2(float x) { return __builtin_amdgcn_exp2f(x); }
__device__ inline unsigned pk4fp8(float a, float b, float c, float d) {
    int r = __builtin_amdgcn_cvt_pk_fp8_f32(a, b, 0, false);
    r = __builtin_amdgcn_cvt_pk_fp8_f32(c, d, r, true);
    return (unsigned)r;
}
__device__ inline f32x16 zero16() {
    f32x16 v;
    #pragma unroll
    for (int i = 0; i < 16; ++i) v[i] = 0.0f;
    return v;
}
__device__ inline f32x16 mfma32(short8 a, short8 b, f32x16 c) {
    return __builtin_amdgcn_mfma_f32_32x32x16_bf16(a, b, c, 0, 0, 0);
}
// MX-scaled fp8 K=64, identity scales (e8m0 0x7F = 2^0)
__device__ inline f32x16 mfma64s(int32x8 a, int32x8 b, f32x16 c) {
    return __builtin_amdgcn_mfma_scale_f32_32x32x64_f8f6f4(
        a, b, c, 0 /*cbsz: fp8*/, 0 /*blgp: fp8*/, 0, 0x7F, 0, 0x7F);
}

// ---------------------------------------------------------------------------
// prep: blocks 0..255: transpose+bf16 x -> xT[b][p][c] (via LDS).
//       blocks 256..295: pack W -> Wfrag[gs][lane][8] in MFMA B-frag order.
// ---------------------------------------------------------------------------
__global__ __launch_bounds__(256, 2) void prep_kernel(
    const float* __restrict__ x,
    const float* __restrict__ Wq, const float* __restrict__ Wk,
    const float* __restrict__ Wv,
    unsigned short* __restrict__ xT, unsigned short* __restrict__ Wfrag)
{
    const int t = threadIdx.x;
    const int bid = blockIdx.x;
    if (bid < 256) {
        __shared__ unsigned short xs[256 * 68];
        const int b = bid >> 6, u = bid & 63;
        const int p0 = u * 64;
        const float* xb = x + (size_t)b * CC * NPIX + p0;
        #pragma unroll
        for (int k = 0; k < 16; ++k) {
            int c = (t >> 4) + 16 * k;
            int p4 = (t & 15) * 4;
            float4 v = *(const float4*)(xb + (size_t)c * NPIX + p4);
            *(uint2*)&xs[c * 68 + p4] = make_uint2(pkbf(v.x, v.y), pkbf(v.z, v.w));
        }
        __syncthreads();
        const int w = t >> 6, l = t & 63;
        const int c8 = l & 31;
        #pragma unroll
        for (int i = 0; i < 8; ++i) {
            int p = i * 8 + w * 2 + (l >> 5);
            unsigned short tmp[8];
            #pragma unroll
            for (int j = 0; j < 8; ++j) tmp[j] = xs[(c8 * 8 + j) * 68 + p];
            uint4 o;
            o.x = tmp[0] | ((unsigned)tmp[1] << 16);
            o.y = tmp[2] | ((unsigned)tmp[3] << 16);
            o.z = tmp[4] | ((unsigned)tmp[5] << 16);
            o.w = tmp[6] | ((unsigned)tmp[7] << 16);
            *(uint4*)(xT + (size_t)(b * NPIX + p0 + p) * 256 + c8 * 8) = o;
        }
    } else {
        const int wb = bid - 256;            // 0..39
        const int l = t & 63, rr = t >> 6;   // rr 0..3
        #pragma unroll
        for (int e = 0; e < 4; ++e) {
            int gs = wb * 4 + e;             // 0..159
            int g = gs >> 4, s = gs & 15;
            const float* src; float scale = 1.0f; int oc0 = 0;
            if (g == 0)      { src = Wq; scale = LOG2E; }
            else if (g == 1) { src = Wk; }
            else             { src = Wv; oc0 = (g - 2) * 32; }
            int row = oc0 + (l & 31);
            int kb2 = 16 * s + 8 * (l >> 5) + rr * 2;
            float v0 = src[(size_t)row * CC + kb2] * scale;
            float v1 = src[(size_t)row * CC + kb2 + 1] * scale;
            *(unsigned*)(Wfrag + (size_t)(gs * 64 + l) * 8 + rr * 2) = pkbf(v0, v1);
        }
    }
}

// ---------------------------------------------------------------------------
// proj: block = 5 waves (320 thr) sharing one LDS x-tile; wave = one ocg x
// 64 px. qT/kT bf16 (q pre-scaled log2e); V written fp8-e4m3 into
// vI[b][j64][cg][lane: jhalf*32+c][32B] (byte = j&31 — K=64 A-frag order).
// ---------------------------------------------------------------------------
__global__ __launch_bounds__(320, 3) void proj_mfma(
    const unsigned short* __restrict__ xT, const unsigned short* __restrict__ Wfrag,
    const float* __restrict__ mask,
    const float* __restrict__ bq, const float* __restrict__ bk,
    const float* __restrict__ bv,
    unsigned short* __restrict__ qT, unsigned short* __restrict__ kT,
    unsigned char* __restrict__ vI)
{
    __shared__ unsigned short xls[64 * 260];
    const int t = threadIdx.x;
    const int w = t >> 6, l = t & 63, L = l & 31, h = l >> 5;
    const int bid = blockIdx.x;
    const int b    = (bid >> 1) & 3;                 // XCD-pinned by batch
    const int u    = ((bid >> 3) << 1) | (bid & 1);  // 0..127
    const int p0   = (u >> 1) * 64;
    const int half = u & 1;
    const int ocg  = half * 5 + w;                   // 0=q 1=k 2..4 / 5..9 v

    const unsigned short* xg = xT + (size_t)(b * NPIX + p0) * 256;
    #pragma unroll
    for (int r = 0; r < 7; ++r) {
        int idx = r * 2560 + t * 8;
        if (idx < 16384) {
            uint4 d = *(const uint4*)(xg + idx);
            int p = idx >> 8, c = idx & 255;
            *(uint2*)&xls[p * 260 + c]     = make_uint2(d.x, d.y);
            *(uint2*)&xls[p * 260 + c + 4] = make_uint2(d.z, d.w);
        }
    }

    FragU wf[16];
    const unsigned short* wp = Wfrag + (size_t)(ocg * 16 * 64 + l) * 8;
    #pragma unroll
    for (int s = 0; s < 16; ++s) wf[s].v = *(const short8*)(wp + s * 512);

    float bcol;
    if (ocg == 0)      bcol = bq[L] * LOG2E;
    else if (ocg == 1) bcol = bk[L];
    else               bcol = bv[(ocg - 2) * 32 + L];
    const float* mb = mask + (size_t)b * NPIX;
    __syncthreads();

    #pragma unroll
    for (int mt = 0; mt < 2; ++mt) {
        const int pp = 32 * mt;
        f32x16 acc = zero16();
        #pragma unroll
        for (int s = 0; s < 16; ++s) {
            FragU af;
            const unsigned short* ap = &xls[(pp + L) * 260 + 16 * s + 8 * h];
            af.d[0] = *(const uint2*)(ap);
            af.d[1] = *(const uint2*)(ap + 4);
            acc = mfma32(af.v, wf[s].v, acc);
        }
        if (ocg < 2) {
            unsigned short* dst = (ocg ? kT : qT) + (size_t)b * NPIX * 32;
            #pragma unroll
            for (int r = 0; r < 16; ++r) {
                int prow = (r & 3) + 8 * (r >> 2) + 4 * h;
                float mv = mb[p0 + pp + prow];
                dst[(size_t)(p0 + pp + prow) * 32 + L] = bf1((acc[r] + bcol) * mv);
            }
        } else {
            const int cg = ocg - 2;
            const int jb32 = p0 + pp;                // 32-j block base
            unsigned char* dst = vI + (size_t)b * (1 << 20)
                + (size_t)(jb32 >> 6) * 16384 + cg * 2048
                + (((jb32 >> 5) & 1) * 32 + L) * 32 + 4 * h;
            #pragma unroll
            for (int m = 0; m < 4; ++m) {
                unsigned pk = pk4fp8(acc[4*m]   + bcol, acc[4*m+1] + bcol,
                                     acc[4*m+2] + bcol, acc[4*m+3] + bcol);
                *(unsigned*)(dst + 8 * m) = pk;
            }
        }
    }
}

// ---------------------------------------------------------------------------
// attn: R9 per-wave structure (acc[8], 64-j iters, wave-local exp2 softmax,
// MX-scaled fp8 K=64 PV) with TWO 32-q tiles fused per 512-thread block.
// Wave pair (w, w+4) = same j-quarter, different q-tile -> same SIMD, shares
// the K/V byte stream through L1 (halves chip-wide L2 traffic). 1 block/CU.
// ---------------------------------------------------------------------------
__global__ __launch_bounds__(512, 2) void attn_mfma(
    const unsigned short* __restrict__ qT, const unsigned short* __restrict__ kT,
    const unsigned char* __restrict__ vI, const float* __restrict__ x,
    const float* __restrict__ gamma, float* __restrict__ out)
{
    __shared__ float mls[2][2][4][32];
    __shared__ float obuf[8][2048];

    const int t = threadIdx.x;
    const int wave = t >> 6, l = t & 63, L = l & 31, h = l >> 5;
    const int qt = wave >> 2;                      // q-tile within block
    const int w  = wave & 3;                       // j-quarter
    const int bid = blockIdx.x;
    const int b  = (bid >> 1) & 3;                 // XCD-pinned by batch
    const int it = (bid >> 3) * 2 + (bid & 1);     // 0..63
    const int i0 = it * 64 + qt * 32;

    const unsigned short* qrow = qT + ((size_t)b * NPIX + i0 + L) * 32 + 8 * h;
    short8 qf0 = *(const short8*)(qrow);
    short8 qf1 = *(const short8*)(qrow + 16);

    const int jbase = w * 1024;
    // K stream: one byte pointer, advanced 4096 B/iter; imm offsets 0/32/2048/2080
    const unsigned char* kp = (const unsigned char*)kT
        + (size_t)b * NPIX * 64 + (size_t)jbase * 64 + (size_t)L * 64 + 16 * h;
    short8 ka0 = *(const short8*)(kp);
    short8 ka1 = *(const short8*)(kp + 32);
    short8 kb0 = *(const short8*)(kp + 2048);
    short8 kb1 = *(const short8*)(kp + 2080);
    kp += 4096;
    // V stream: lane l reads its 32B at vp + cg*2048; advance 16384 B/iter
    const unsigned char* vp = vI + (size_t)b * (1 << 20)
        + (size_t)(jbase >> 6) * 16384 + (size_t)l * 32;

    f32x16 acc[8];
    #pragma unroll
    for (int cg = 0; cg < 8; ++cg) acc[cg] = zero16();
    float m_run = -INFINITY, l_run = 0.0f;

    for (int itr = 0; itr < 16; ++itr) {
        // ---- S(n) ----
        f32x16 s0 = zero16(), s1 = zero16();
        s0 = mfma32(ka0, qf0, s0);
        s0 = mfma32(ka1, qf1, s0);
        s1 = mfma32(kb0, qf0, s1);
        s1 = mfma32(kb1, qf1, s1);

        // ---- K prefetch (n+1) ----  (last iter reads past kT: valid ws mem)
        ka0 = *(const short8*)(kp);
        ka1 = *(const short8*)(kp + 32);
        kb0 = *(const short8*)(kp + 2048);
        kb1 = *(const short8*)(kp + 2080);
        kp += 4096;

        // ---- V loads, first half (cg 0..3) — covered by softmax below ----
        V8 vv[4];
        #pragma unroll
        for (int cg = 0; cg < 4; ++cg) {
            vv[cg].q[0] = *(const uint4*)(vp + cg * 2048);
            vv[cg].q[1] = *(const uint4*)(vp + cg * 2048 + 16);
        }

        // ---- wave-local online softmax (exp2 domain, hysteresis, trees) ----
        float t0 = s0[0], t1 = s0[1], t2 = s0[2], t3 = s0[3];
        #pragma unroll
        for (int r = 4; r < 16; r += 4) {
            t0 = fmaxf(t0, s0[r]);     t1 = fmaxf(t1, s0[r + 1]);
            t2 = fmaxf(t2, s0[r + 2]); t3 = fmaxf(t3, s0[r + 3]);
        }
        #pragma unroll
        for (int r = 0; r < 16; r += 4) {
            t0 = fmaxf(t0, s1[r]);     t1 = fmaxf(t1, s1[r + 1]);
            t2 = fmaxf(t2, s1[r + 2]); t3 = fmaxf(t3, s1[r + 3]);
        }
        float tmax = fmaxf(fmaxf(t0, t1), fmaxf(t2, t3));
        tmax = fmaxf(tmax, __shfl_xor(tmax, 32));
        if (__ballot(tmax > m_run + 3.0f)) {
            float m_new = fmaxf(m_run, tmax);
            float alpha = ex2(m_run - m_new);   // first iter: ex2(-inf)=0
            l_run *= alpha;
            #pragma unroll
            for (int cg = 0; cg < 8; ++cg)
                #pragma unroll
                for (int r = 0; r < 16; ++r) acc[cg][r] *= alpha;
            m_run = m_new;
        }

        float z0 = 0, z1 = 0, z2 = 0, z3 = 0;
        #pragma unroll
        for (int r = 0; r < 16; r += 4) {
            s0[r]   = ex2(s0[r]   - m_run); z0 += s0[r];
            s0[r+1] = ex2(s0[r+1] - m_run); z1 += s0[r+1];
            s0[r+2] = ex2(s0[r+2] - m_run); z2 += s0[r+2];
            s0[r+3] = ex2(s0[r+3] - m_run); z3 += s0[r+3];
        }
        #pragma unroll
        for (int r = 0; r < 16; r += 4) {
            s1[r]   = ex2(s1[r]   - m_run); z0 += s1[r];
            s1[r+1] = ex2(s1[r+1] - m_run); z1 += s1[r+1];
            s1[r+2] = ex2(s1[r+2] - m_run); z2 += s1[r+2];
            s1[r+3] = ex2(s1[r+3] - m_run); z3 += s1[r+3];
        }
        float ssum = (z0 + z1) + (z2 + z3);
        ssum += __shfl_xor(ssum, 32);
        l_run += ssum;

        // ---- pack P, exchange, build K=64 B-frag ----
        unsigned u0[4], u1[4], p0[4], p1[4];
        #pragma unroll
        for (int m = 0; m < 4; ++m) {
            u0[m] = pk4fp8(s0[4*m], s0[4*m+1], s0[4*m+2], s0[4*m+3]);
            u1[m] = pk4fp8(s1[4*m], s1[4*m+1], s1[4*m+2], s1[4*m+3]);
        }
        #pragma unroll
        for (int q = 0; q < 4; ++q) {
            p0[q] = (unsigned)__shfl_xor((int)u0[q], 32);
            p1[q] = (unsigned)__shfl_xor((int)u1[q], 32);
        }
        B8 bf;
        #pragma unroll
        for (int m = 0; m < 4; ++m) {
            unsigned oh = h ? u1[m] : u0[m];
            unsigned ph = h ? p1[m] : p0[m];
            bf.u[2*m]     = h ? ph : oh;   // dword r=2m:   j 8m+0..3
            bf.u[2*m + 1] = h ? oh : ph;   // dword r=2m+1: j 8m+4..7
        }

        // ---- PV: 8 MX-scaled K=64 MFMAs ----
        #pragma unroll
        for (int cg = 0; cg < 4; ++cg) acc[cg] = mfma64s(vv[cg].iv, bf.iv, acc[cg]);
        #pragma unroll
        for (int cg = 0; cg < 4; ++cg) {
            vv[cg].q[0] = *(const uint4*)(vp + (cg + 4) * 2048);
            vv[cg].q[1] = *(const uint4*)(vp + (cg + 4) * 2048 + 16);
        }
        #pragma unroll
        for (int cg = 0; cg < 4; ++cg) acc[cg + 4] = mfma64s(vv[cg].iv, bf.iv, acc[cg + 4]);
        vp += 16384;
    }

    // ---- merge 4 j-quarter waves per q-tile ----
    if (h == 0) { mls[0][qt][w][L] = m_run; mls[1][qt][w][L] = l_run; }
    __syncthreads();
    float m0 = mls[0][qt][0][L], m1 = mls[0][qt][1][L];
    float m2 = mls[0][qt][2][L], m3 = mls[0][qt][3][L];
    float ms = fmaxf(fmaxf(m0, m1), fmaxf(m2, m3));
    float f0 = ex2(m0 - ms), f1 = ex2(m1 - ms);
    float f2 = ex2(m2 - ms), f3 = ex2(m3 - ms);
    float lstar = f0 * mls[1][qt][0][L] + f1 * mls[1][qt][1][L]
                + f2 * mls[1][qt][2][L] + f3 * mls[1][qt][3][L];
    float fw = (w == 0) ? f0 : (w == 1) ? f1 : (w == 2) ? f2 : f3;
    const float scale = gamma[0] / lstar;

    #pragma unroll
    for (int cg = 0; cg < 8; ++cg)
        #pragma unroll
        for (int r = 0; r < 16; ++r) acc[cg][r] *= fw;

    const int tt = t & 255, qt2 = t >> 8;
    const int ti = tt & 31, trow = tt >> 5;
    const int i0b = it * 64 + qt2 * 32;
    for (int ck = 0; ck < 4; ++ck) {
        #pragma unroll
        for (int half = 0; half < 2; ++half) {
            #pragma unroll
            for (int r = 0; r < 16; ++r) {
                int prow = (r & 3) + 8 * (r >> 2) + 4 * h;
                obuf[qt * 4 + w][half * 1024 + prow * 32 + L] = acc[2 * ck + half][r];
            }
        }
        __syncthreads();
        #pragma unroll
        for (int rr = 0; rr < 8; ++rr) {
            int cr = trow + 8 * rr;
            int idx = cr * 32 + ti;
            float sum = (obuf[qt2*4 + 0][idx] + obuf[qt2*4 + 1][idx])
                      + (obuf[qt2*4 + 2][idx] + obuf[qt2*4 + 3][idx]);
            size_t gi = ((size_t)b * CC + ck * 64 + cr) * NPIX + i0b + ti;
            out[gi] = scale * sum + x[gi];
        }
        __syncthreads();
    }
}

// ---------------------------------------------------------------------------
extern "C" void kernel_launch(void* const* d_in, const int* in_sizes, int n_in,
                              void* d_out, int out_size, void* d_ws, size_t ws_size,
                              hipStream_t stream) {
    const float* x     = (const float*)d_in[0];
    const float* mask  = (const float*)d_in[1];
    const float* Wq    = (const float*)d_in[2];
    const float* bq    = (const float*)d_in[3];
    const float* Wk    = (const float*)d_in[4];
    const float* bk    = (const float*)d_in[5];
    const float* Wv    = (const float*)d_in[6];
    const float* bv    = (const float*)d_in[7];
    const float* gamma = (const float*)d_in[8];
    float* out = (float*)d_out;

    unsigned short* ws = (unsigned short*)d_ws;
    unsigned short* qT = ws;                                   // [B][N][32] bf16
    unsigned short* kT = qT + (size_t)BATCH * NPIX * 32;       // [B][N][32] bf16
    unsigned char*  vI = (unsigned char*)(kT + (size_t)BATCH * NPIX * 32);  // [B][64][8][64][32] fp8
    unsigned short* xT = (unsigned short*)(vI + (size_t)BATCH * CC * NPIX); // [B][N][256] bf16
    unsigned short* Wfrag = xT + (size_t)BATCH * NPIX * 256;   // [160][64][8] bf16

    prep_kernel<<<296, 256, 0, stream>>>(x, Wq, Wk, Wv, xT, Wfrag);
    proj_mfma<<<512, 320, 0, stream>>>(xT, Wfrag, mask, bq, bk, bv, qT, kT, vI);
    attn_mfma<<<256, 512, 0, stream>>>(qT, kT, vI, x, gamma, out);
}